// Round 9
// baseline (100.952 us; speedup 1.0000x reference)
//
#include <hip/hip_runtime.h>
#include <stdint.h>

typedef unsigned short u16;
typedef __attribute__((ext_vector_type(8))) short bf16x8;
typedef __attribute__((ext_vector_type(8))) u16  u16x8;
typedef __attribute__((ext_vector_type(4))) float f32x4;

// Problem constants
static constexpr int BATCH  = 32;
static constexpr int SEQ    = 1000;
static constexpr int DIM    = 64;
static constexpr int HOUT   = 512;
static constexpr int MINLEN = 985;   // 1000 - 16 + 1

// ws layout (bytes)
static constexpr size_t PB_OFF = 0;            // posb f32: 985*512*4 = 1.97 MB
static constexpr size_t XB_OFF = 2u << 20;     // xb bf16: padded
static constexpr size_t WF_OFF = 8u << 20;     // Wp packed bf16: 1 MiB
// xb padded so max accessed row (l0=896 + 142 = 1038) is in-bounds & zero:
static constexpr int    XB_TOTAL = 2048000 + 8192;   // = 2048*1004, rows 0..1063

__device__ inline u16 f2bf(float f) {
  union { float f; uint32_t u; } v; v.f = f;
  uint32_t r = v.u + 0x7fffu + ((v.u >> 16) & 1u);
  return (u16)(r >> 16);
}

// ---- prep (single kernel, 3 segments) -------------------------------------
// bid < 1004          : x f32 -> bf16 (+ zero pad tail rows)
// 1004 <= bid < 1260  : fold W, PACK into MFMA-fragment order:
//   packed u16 idx = ((h>>4)*32 + (k>>5))*512 + ((k>>3)&3)*128 + (h&15)*8 + (k&7)
//   -> fragment (hgrp, kt) is contiguous 1 KB; lane l reads 16B at l*8
// bid >= 1260         : posb[l,h] = pos[l,h] + mean_bias[h]
__global__ void pe_prep(const float* __restrict__ x,
                        const float* __restrict__ W0, const float* __restrict__ W1,
                        const float* __restrict__ W2, const float* __restrict__ b0,
                        const float* __restrict__ b1, const float* __restrict__ b2,
                        const float* __restrict__ pos,
                        u16* __restrict__ xb, u16* __restrict__ Wp,
                        float* __restrict__ posb) {
  int bid = blockIdx.x;
  if (bid < 1004) {
    int i = (bid * 256 + threadIdx.x) * 8;
    u16x8 o;
    if (i < 2048000) {
      const float4* p = (const float4*)(x + i);
      float4 a = p[0], c = p[1];
      o[0] = f2bf(a.x); o[1] = f2bf(a.y); o[2] = f2bf(a.z); o[3] = f2bf(a.w);
      o[4] = f2bf(c.x); o[5] = f2bf(c.y); o[6] = f2bf(c.z); o[7] = f2bf(c.w);
    } else {
      o = (u16x8)(0);
    }
    *(u16x8*)(xb + i) = o;
  } else if (bid < 1260) {
    int j  = (bid - 1004) * 256 + threadIdx.x;   // one 8-elem k-chunk
    int h  = j >> 7;
    int kc = j & 127;                            // k = kc*8 + e
    float v[8];
    const float4* w2 = (const float4*)(W2 + h * 1024 + kc * 8);
    float4 a = w2[0], c = w2[1];
    v[0]=a.x; v[1]=a.y; v[2]=a.z; v[3]=a.w; v[4]=c.x; v[5]=c.y; v[6]=c.z; v[7]=c.w;
    if (kc < 64) {
      const float4* w1 = (const float4*)(W1 + h * 512 + kc * 8);
      float4 d = w1[0], e = w1[1];
      v[0]+=d.x; v[1]+=d.y; v[2]+=d.z; v[3]+=d.w; v[4]+=e.x; v[5]+=e.y; v[6]+=e.z; v[7]+=e.w;
    }
    if (kc < 32) {
      const float4* w0 = (const float4*)(W0 + h * 256 + kc * 8);
      float4 d = w0[0], e = w0[1];
      v[0]+=d.x; v[1]+=d.y; v[2]+=d.z; v[3]+=d.w; v[4]+=e.x; v[5]+=e.y; v[6]+=e.z; v[7]+=e.w;
    }
    u16x8 o;
    #pragma unroll
    for (int e = 0; e < 8; ++e) o[e] = f2bf(v[e] * (1.0f / 3.0f));
    size_t dst = ((size_t)(h >> 4) * 32 + (kc >> 2)) * 512 + (kc & 3) * 128 + (h & 15) * 8;
    *(u16x8*)(Wp + dst) = o;
  } else {
    int idx = (bid - 1260) * 256 + threadIdx.x;  // float4 index into posb
    if (idx < MINLEN * (HOUT / 4)) {
      int l  = idx >> 7;
      int h4 = idx & 127;
      float4 p  = ((const float4*)pos)[(size_t)l * 128 + h4];
      float4 a0 = ((const float4*)b0)[h4];
      float4 a1 = ((const float4*)b1)[h4];
      float4 a2 = ((const float4*)b2)[h4];
      float4 o;
      o.x = p.x + (a0.x + a1.x + a2.x) * (1.0f / 3.0f);
      o.y = p.y + (a0.y + a1.y + a2.y) * (1.0f / 3.0f);
      o.z = p.z + (a0.z + a1.z + a2.z) * (1.0f / 3.0f);
      o.w = p.w + (a0.w + a1.w + a2.w) * (1.0f / 3.0f);
      ((float4*)posb)[idx] = o;
    }
  }
}

// ---- GEMM: out[b,l,h] = dot(window) + posb[l,h]
// 128x128 tile, 4 waves (2m x 2n), wave 64x64 -> acc[4][4], BK=32, 32 kt.
// NO LDS, NO barriers, NO prologue staging:
//   A: sliding-window fragments read DIRECTLY from xb (bf16). Per-block A
//      panel = 18 KB -> L1-resident; a wave's 4 loads cover a dense 16-row
//      x 128B region (every line fully consumed across g/kt&1).
//      addr = Ap + (m*16 + (kt>>1))*64 + (kt&1)*32   (u16), 16B aligned.
//   B: packed Wp (1 MB, L2-resident) coalesced dwordx4 fragment loads,
//      1-kt register double buffer (bA/bB, unroll-2, static indexing).
// Waves are fully independent -> natural phase stagger; setprio(1) wraps
// each 16-MFMA burst (T5's independent-wave regime).
__global__ __launch_bounds__(256, 4) void pe_gemm(
    const u16* __restrict__ xb, const u16* __restrict__ Wp,
    const float* __restrict__ posb, float* __restrict__ out) {
  const int t    = threadIdx.x;
  const int w    = t >> 6;
  const int lane = t & 63;
  const int b    = blockIdx.z;
  const int l0   = blockIdx.y * 128;
  const int n0   = blockIdx.x * 128;
  const int wr   = w >> 1;             // 0..1 -> 64-row band
  const int wc   = w & 1;              // 0..1 -> 64-col band
  const int lr   = lane & 15;
  const int g    = lane >> 4;          // 0..3

  // this wave's packed-B base: hgrps [(n0>>4)+wc*4, +4)
  const u16* Bp = Wp + ((size_t)((n0 >> 4) + wc * 4) * 32) * 512 + lane * 8;
  // this lane's A base: row (l0 + wr*64 + lr), d-offset g*8
  const u16* Ap = xb + (size_t)b * (SEQ * DIM)
                     + (size_t)(l0 + wr * 64 + lr) * 64 + g * 8;

  bf16x8 bA[4], bB[4];
  #pragma unroll
  for (int n = 0; n < 4; ++n)
    bA[n] = *(const bf16x8*)(Bp + (size_t)(n * 32) * 512);

  f32x4 acc[4][4] = {};

  #define A_READS(kt_, aF_)                                                   \
    _Pragma("unroll")                                                         \
    for (int m = 0; m < 4; ++m)                                               \
      aF_[m] = *(const bf16x8*)(Ap + (m * 16 + ((kt_) >> 1)) * 64             \
                                   + ((kt_) & 1) * 32);
  #define B_LOADS(kt_, dst_)                                                  \
    _Pragma("unroll")                                                         \
    for (int n = 0; n < 4; ++n)                                               \
      dst_[n] = *(const bf16x8*)(Bp + (size_t)(n * 32 + (kt_)) * 512);
  #define MFMAS(aF_, bF_)                                                     \
    __builtin_amdgcn_s_setprio(1);                                            \
    _Pragma("unroll")                                                         \
    for (int m = 0; m < 4; ++m)                                               \
      _Pragma("unroll")                                                       \
      for (int n = 0; n < 4; ++n)                                             \
        acc[m][n] = __builtin_amdgcn_mfma_f32_16x16x32_bf16(aF_[m], bF_[n],   \
                                                            acc[m][n], 0, 0, 0); \
    __builtin_amdgcn_s_setprio(0);

  for (int kt = 0; kt < 32; kt += 2) {
    bf16x8 aF[4];
    if (kt + 1 < 32) { B_LOADS(kt + 1, bB); }
    A_READS(kt, aF);
    MFMAS(aF, bA);
    if (kt + 2 < 32) { B_LOADS(kt + 2, bA); }
    A_READS(kt + 1, aF);
    MFMAS(aF, bB);
  }
  #undef A_READS
  #undef B_LOADS
  #undef MFMAS

  // ---- epilogue: D row=(lane>>4)*4+r, col=lane&15 (m89); posb fused ----
  #pragma unroll
  for (int n = 0; n < 4; ++n) {
    const int h = n0 + wc * 64 + n * 16 + lr;
    #pragma unroll
    for (int m = 0; m < 4; ++m) {
      const int rowb = l0 + wr * 64 + m * 16 + (g << 2);
      #pragma unroll
      for (int r = 0; r < 4; ++r) {
        const int l = rowb + r;
        if (l < MINLEN) {
          out[((size_t)b * MINLEN + l) * HOUT + h] =
              acc[m][n][r] + posb[(size_t)l * HOUT + h];
        }
      }
    }
  }
}

extern "C" void kernel_launch(void* const* d_in, const int* in_sizes, int n_in,
                              void* d_out, int out_size, void* d_ws, size_t ws_size,
                              hipStream_t stream) {
  const float* x   = (const float*)d_in[0];
  const float* W0  = (const float*)d_in[1];
  const float* b0  = (const float*)d_in[2];
  const float* W1  = (const float*)d_in[3];
  const float* b1  = (const float*)d_in[4];
  const float* W2  = (const float*)d_in[5];
  const float* b2  = (const float*)d_in[6];
  const float* pos = (const float*)d_in[7];
  float* out = (float*)d_out;

  char*  ws   = (char*)d_ws;
  float* posb = (float*)(ws + PB_OFF);
  u16*   xbf  = (u16*)(ws + XB_OFF);
  u16*   Wp   = (u16*)(ws + WF_OFF);

  // prep: 1004 xb blocks + 256 fold/pack blocks + 493 posb blocks
  hipLaunchKernelGGL(pe_prep, dim3(1004 + 256 + 493), dim3(256), 0, stream,
                     x, W0, W1, W2, b0, b1, b2, pos, xbf, Wp, posb);
  // 4 n-tiles x 8 m-tiles x 32 batch = 1024 blocks = exactly 4/CU
  hipLaunchKernelGGL(pe_gemm, dim3(HOUT / 128, 8, BATCH), dim3(256), 0, stream,
                     xbf, Wp, posb, out);
}

// Round 10
// 66.674 us; speedup vs baseline: 1.5141x; 1.5141x over previous
//
#include <hip/hip_runtime.h>
#include <stdint.h>

typedef unsigned short u16;
typedef __attribute__((ext_vector_type(8))) short bf16x8;
typedef __attribute__((ext_vector_type(8))) u16  u16x8;
typedef __attribute__((ext_vector_type(4))) float f32x4;

// Problem constants
static constexpr int BATCH  = 32;
static constexpr int SEQ    = 1000;
static constexpr int DIM    = 64;
static constexpr int HOUT   = 512;
static constexpr int MINLEN = 985;   // 1000 - 16 + 1
static constexpr int AROWS  = 80;    // 64-row tile + 15 window ext + 1 pad

// ws layout (bytes)
static constexpr size_t PB_OFF = 0;            // posb f32: 985*512*4 = 1.97 MB
static constexpr size_t XB_OFF = 2u << 20;     // xb bf16: padded
static constexpr size_t WF_OFF = 8u << 20;     // Wp packed bf16: 1 MiB
// max accessed xb element: b=31 base 1,984,000 + row 1039*64 + 64 = 2,050,560
static constexpr int    XB_TOTAL = 2048000 + 8192;   // = 2048*1004 > 2,050,560 ✓

__device__ inline u16 f2bf(float f) {
  union { float f; uint32_t u; } v; v.f = f;
  uint32_t r = v.u + 0x7fffu + ((v.u >> 16) & 1u);
  return (u16)(r >> 16);
}

// ---- prep (single kernel, 3 segments) -------------------------------------
// bid < 1004          : x f32 -> bf16 (+ zero pad tail rows)
// 1004 <= bid < 1260  : fold W, PACK into MFMA-fragment order:
//   packed u16 idx = ((h>>4)*32 + (k>>5))*512 + ((k>>3)&3)*128 + (h&15)*8 + (k&7)
//   -> fragment (hgrp, kt) is contiguous 1 KB; lane l reads 16B at l*8
// bid >= 1260         : posb[l,h] = pos[l,h] + mean_bias[h]
__global__ void pe_prep(const float* __restrict__ x,
                        const float* __restrict__ W0, const float* __restrict__ W1,
                        const float* __restrict__ W2, const float* __restrict__ b0,
                        const float* __restrict__ b1, const float* __restrict__ b2,
                        const float* __restrict__ pos,
                        u16* __restrict__ xb, u16* __restrict__ Wp,
                        float* __restrict__ posb) {
  int bid = blockIdx.x;
  if (bid < 1004) {
    int i = (bid * 256 + threadIdx.x) * 8;
    u16x8 o;
    if (i < 2048000) {
      const float4* p = (const float4*)(x + i);
      float4 a = p[0], c = p[1];
      o[0] = f2bf(a.x); o[1] = f2bf(a.y); o[2] = f2bf(a.z); o[3] = f2bf(a.w);
      o[4] = f2bf(c.x); o[5] = f2bf(c.y); o[6] = f2bf(c.z); o[7] = f2bf(c.w);
    } else {
      o = (u16x8)(0);
    }
    *(u16x8*)(xb + i) = o;
  } else if (bid < 1260) {
    int j  = (bid - 1004) * 256 + threadIdx.x;   // one 8-elem k-chunk
    int h  = j >> 7;
    int kc = j & 127;                            // k = kc*8 + e
    float v[8];
    const float4* w2 = (const float4*)(W2 + h * 1024 + kc * 8);
    float4 a = w2[0], c = w2[1];
    v[0]=a.x; v[1]=a.y; v[2]=a.z; v[3]=a.w; v[4]=c.x; v[5]=c.y; v[6]=c.z; v[7]=c.w;
    if (kc < 64) {
      const float4* w1 = (const float4*)(W1 + h * 512 + kc * 8);
      float4 d = w1[0], e = w1[1];
      v[0]+=d.x; v[1]+=d.y; v[2]+=d.z; v[3]+=d.w; v[4]+=e.x; v[5]+=e.y; v[6]+=e.z; v[7]+=e.w;
    }
    if (kc < 32) {
      const float4* w0 = (const float4*)(W0 + h * 256 + kc * 8);
      float4 d = w0[0], e = w0[1];
      v[0]+=d.x; v[1]+=d.y; v[2]+=d.z; v[3]+=d.w; v[4]+=e.x; v[5]+=e.y; v[6]+=e.z; v[7]+=e.w;
    }
    u16x8 o;
    #pragma unroll
    for (int e = 0; e < 8; ++e) o[e] = f2bf(v[e] * (1.0f / 3.0f));
    size_t dst = ((size_t)(h >> 4) * 32 + (kc >> 2)) * 512 + (kc & 3) * 128 + (h & 15) * 8;
    *(u16x8*)(Wp + dst) = o;
  } else {
    int idx = (bid - 1260) * 256 + threadIdx.x;  // float4 index into posb
    if (idx < MINLEN * (HOUT / 4)) {
      int l  = idx >> 7;
      int h4 = idx & 127;
      float4 p  = ((const float4*)pos)[(size_t)l * 128 + h4];
      float4 a0 = ((const float4*)b0)[h4];
      float4 a1 = ((const float4*)b1)[h4];
      float4 a2 = ((const float4*)b2)[h4];
      float4 o;
      o.x = p.x + (a0.x + a1.x + a2.x) * (1.0f / 3.0f);
      o.y = p.y + (a0.y + a1.y + a2.y) * (1.0f / 3.0f);
      o.z = p.z + (a0.z + a1.z + a2.z) * (1.0f / 3.0f);
      o.w = p.w + (a0.w + a1.w + a2.w) * (1.0f / 3.0f);
      ((float4*)posb)[idx] = o;
    }
  }
}

__device__ inline void gload_lds16(const void* g, void* l) {
  __builtin_amdgcn_global_load_lds(
      (const __attribute__((address_space(1))) uint32_t*)g,
      (__attribute__((address_space(3))) uint32_t*)l, 16, 0, 0);
}

// ---- GEMM: out[b,l,h] = dot(window) + posb[l,h]
// MAX-DESYNC topology: ONE WAVE PER BLOCK (64 threads), 64x64 output tile,
// acc[4][4], BK=32, 32 kt. Inner loop byte-identical to R6:
//   A: wave-private sliding-window panel (80 rows, 10 KB) in LDS, staged once
//      via 10 gload_lds chunks (pre-swizzled source, rule 21), read with
//      slot8 ^= row&7 swizzled ds_read_b128.
//   B: packed Wp (1 MB, L2-resident) coalesced dwordx4 fragment loads,
//      1-kt register double buffer.
// ZERO barriers; 16 independent waves/CU (LDS 16x10KB = 160KB, regs ~130)
// each at its own pipeline phase -> stalls of one wave filled by others.
__global__ __launch_bounds__(64, 8) void pe_gemm(
    const u16* __restrict__ xb, const u16* __restrict__ Wp,
    const float* __restrict__ posb, float* __restrict__ out) {
  __shared__ u16 ldsA[AROWS * 64];     // 10,240 B, wave-private

  const int lane = threadIdx.x;        // 0..63
  const int b    = blockIdx.z;
  const int l0   = blockIdx.y * 64;
  const int n0   = blockIdx.x * 64;
  const int lr   = lane & 15;
  const int g    = lane >> 4;          // 0..3

  // packed-B base: hgrps [n0>>4, +4)
  const u16* Bp = Wp + ((size_t)(n0 >> 4) * 32) * 512 + lane * 8;

  // ---- prologue: stage A (10 chunks of 8 rows x 64 u16), then wait ----
  const int srow = lane >> 3;
  const int sca  = ((lane & 7) ^ srow) * 8;          // pre-swizzled source slot
  const u16* Ab  = xb + (size_t)b * (SEQ * DIM) + (size_t)l0 * 64;
  #pragma unroll
  for (int c = 0; c < 10; ++c)
    gload_lds16(Ab + (c * 8 + srow) * 64 + sca, &ldsA[c * 512]);

  bf16x8 bA[4], bB[4];
  #pragma unroll
  for (int n = 0; n < 4; ++n)
    bA[n] = *(const bf16x8*)(Bp + (size_t)(n * 32) * 512);

  __syncthreads();                     // 1-wave block: just the waitcnt drain

  f32x4 acc[4][4] = {};

  #define A_READS(kt_, aF_)                                                   \
    _Pragma("unroll")                                                         \
    for (int m = 0; m < 4; ++m) {                                             \
      int r = lr + m * 16 + ((kt_) >> 1);                                     \
      int s = ((((kt_) & 1) << 2) + g) ^ (r & 7);                             \
      aF_[m] = *(const bf16x8*)&ldsA[r * 64 + s * 8];                         \
    }
  #define B_LOADS(kt_, dst_)                                                  \
    _Pragma("unroll")                                                         \
    for (int n = 0; n < 4; ++n)                                               \
      dst_[n] = *(const bf16x8*)(Bp + (size_t)(n * 32 + (kt_)) * 512);
  #define MFMAS(aF_, bF_)                                                     \
    __builtin_amdgcn_s_setprio(1);                                            \
    _Pragma("unroll")                                                         \
    for (int m = 0; m < 4; ++m)                                               \
      _Pragma("unroll")                                                       \
      for (int n = 0; n < 4; ++n)                                             \
        acc[m][n] = __builtin_amdgcn_mfma_f32_16x16x32_bf16(aF_[m], bF_[n],   \
                                                            acc[m][n], 0, 0, 0); \
    __builtin_amdgcn_s_setprio(0);

  for (int kt = 0; kt < 32; kt += 2) {
    bf16x8 aF[4];
    if (kt + 1 < 32) { B_LOADS(kt + 1, bB); }
    A_READS(kt, aF);
    MFMAS(aF, bA);
    if (kt + 2 < 32) { B_LOADS(kt + 2, bA); }
    A_READS(kt + 1, aF);
    MFMAS(aF, bB);
  }
  #undef A_READS
  #undef B_LOADS
  #undef MFMAS

  // ---- epilogue: D row=(lane>>4)*4+r, col=lane&15 (m89); posb fused ----
  #pragma unroll
  for (int n = 0; n < 4; ++n) {
    const int h = n0 + n * 16 + lr;
    #pragma unroll
    for (int m = 0; m < 4; ++m) {
      const int rowb = l0 + m * 16 + (g << 2);
      #pragma unroll
      for (int r = 0; r < 4; ++r) {
        const int l = rowb + r;
        if (l < MINLEN) {
          out[((size_t)b * MINLEN + l) * HOUT + h] =
              acc[m][n][r] + posb[(size_t)l * HOUT + h];
        }
      }
    }
  }
}

extern "C" void kernel_launch(void* const* d_in, const int* in_sizes, int n_in,
                              void* d_out, int out_size, void* d_ws, size_t ws_size,
                              hipStream_t stream) {
  const float* x   = (const float*)d_in[0];
  const float* W0  = (const float*)d_in[1];
  const float* b0  = (const float*)d_in[2];
  const float* W1  = (const float*)d_in[3];
  const float* b1  = (const float*)d_in[4];
  const float* W2  = (const float*)d_in[5];
  const float* b2  = (const float*)d_in[6];
  const float* pos = (const float*)d_in[7];
  float* out = (float*)d_out;

  char*  ws   = (char*)d_ws;
  float* posb = (float*)(ws + PB_OFF);
  u16*   xbf  = (u16*)(ws + XB_OFF);
  u16*   Wp   = (u16*)(ws + WF_OFF);

  // prep: 1004 xb blocks + 256 fold/pack blocks + 493 posb blocks
  hipLaunchKernelGGL(pe_prep, dim3(1004 + 256 + 493), dim3(256), 0, stream,
                     x, W0, W1, W2, b0, b1, b2, pos, xbf, Wp, posb);
  // 8 n-tiles x 16 m-tiles x 32 batch = 4096 one-wave blocks = 16/CU
  hipLaunchKernelGGL(pe_gemm, dim3(HOUT / 64, 16, BATCH), dim3(64), 0, stream,
                     xbf, Wp, posb, out);
}

// Round 11
// 63.464 us; speedup vs baseline: 1.5907x; 1.0506x over previous
//
#include <hip/hip_runtime.h>
#include <stdint.h>

typedef unsigned short u16;
typedef __attribute__((ext_vector_type(8))) short bf16x8;
typedef __attribute__((ext_vector_type(8))) u16  u16x8;
typedef __attribute__((ext_vector_type(4))) float f32x4;

// Problem constants
static constexpr int BATCH  = 32;
static constexpr int SEQ    = 1000;
static constexpr int DIM    = 64;
static constexpr int HOUT   = 512;
static constexpr int MINLEN = 985;   // 1000 - 16 + 1
static constexpr int AROWS  = 144;   // 128-row tile + 15 window ext + pad

// ws layout (bytes)
static constexpr size_t XB_OFF   = 0;                  // x bf16: 2,048,000 + 4096 pad u16
static constexpr size_t WF_OFF   = 4u << 20;           // Wp packed bf16: 1 MiB
static constexpr size_t BE_OFF   = 5u << 20;           // beff f32: 512
static constexpr int    XB_TOTAL = 2048000 + 4096;     // = 2048*1002, exact

__device__ inline u16 f2bf(float f) {
  union { float f; uint32_t u; } v; v.f = f;
  uint32_t r = v.u + 0x7fffu + ((v.u >> 16) & 1u);
  return (u16)(r >> 16);
}

// ---- prep (single kernel, 3 segments) -------------------------------------
// bid < 1002          : x f32 -> bf16 (+ zero pad tail)
// 1002 <= bid < 1258  : fold W, PACK into MFMA-fragment order:
//   packed u16 idx = ((h>>4)*32 + (k>>5))*512 + ((k>>3)&3)*128 + (h&15)*8 + (k&7)
//   -> fragment (hgrp, kt) is contiguous 1 KB; lane l reads 16B at l*8
// bid >= 1258         : beff = mean bias
__global__ void pe_prep(const float* __restrict__ x,
                        const float* __restrict__ W0, const float* __restrict__ W1,
                        const float* __restrict__ W2, const float* __restrict__ b0,
                        const float* __restrict__ b1, const float* __restrict__ b2,
                        u16* __restrict__ xb, u16* __restrict__ Wp,
                        float* __restrict__ beff) {
  int bid = blockIdx.x;
  if (bid < 1002) {
    int i = (bid * 256 + threadIdx.x) * 8;
    u16x8 o;
    if (i < 2048000) {
      const float4* p = (const float4*)(x + i);
      float4 a = p[0], c = p[1];
      o[0] = f2bf(a.x); o[1] = f2bf(a.y); o[2] = f2bf(a.z); o[3] = f2bf(a.w);
      o[4] = f2bf(c.x); o[5] = f2bf(c.y); o[6] = f2bf(c.z); o[7] = f2bf(c.w);
    } else {
      o = (u16x8)(0);
    }
    *(u16x8*)(xb + i) = o;
  } else if (bid < 1258) {
    int j  = (bid - 1002) * 256 + threadIdx.x;   // one 8-elem k-chunk
    int h  = j >> 7;
    int kc = j & 127;                            // k = kc*8 + e
    float v[8];
    const float4* w2 = (const float4*)(W2 + h * 1024 + kc * 8);
    float4 a = w2[0], c = w2[1];
    v[0]=a.x; v[1]=a.y; v[2]=a.z; v[3]=a.w; v[4]=c.x; v[5]=c.y; v[6]=c.z; v[7]=c.w;
    if (kc < 64) {
      const float4* w1 = (const float4*)(W1 + h * 512 + kc * 8);
      float4 d = w1[0], e = w1[1];
      v[0]+=d.x; v[1]+=d.y; v[2]+=d.z; v[3]+=d.w; v[4]+=e.x; v[5]+=e.y; v[6]+=e.z; v[7]+=e.w;
    }
    if (kc < 32) {
      const float4* w0 = (const float4*)(W0 + h * 256 + kc * 8);
      float4 d = w0[0], e = w0[1];
      v[0]+=d.x; v[1]+=d.y; v[2]+=d.z; v[3]+=d.w; v[4]+=e.x; v[5]+=e.y; v[6]+=e.z; v[7]+=e.w;
    }
    u16x8 o;
    #pragma unroll
    for (int e = 0; e < 8; ++e) o[e] = f2bf(v[e] * (1.0f / 3.0f));
    size_t dst = ((size_t)(h >> 4) * 32 + (kc >> 2)) * 512 + (kc & 3) * 128 + (h & 15) * 8;
    *(u16x8*)(Wp + dst) = o;
  } else {
    int h = (bid - 1258) * 256 + threadIdx.x;
    if (h < HOUT) beff[h] = (b0[h] + b1[h] + b2[h]) * (1.0f / 3.0f);
  }
}

__device__ inline void gload_lds16(const void* g, void* l) {
  __builtin_amdgcn_global_load_lds(
      (const __attribute__((address_space(1))) uint32_t*)g,
      (__attribute__((address_space(3))) uint32_t*)l, 16, 0, 0);
}

// ---- GEMM: out[b,l,h] = dot(window) + beff[h] + pos[l,h]
// R6 base (best at 54.8us) + DEPTH-2 B PREFETCH:
// 128x128 tile, 4 waves (2m x 2n), wave 64x64 -> acc[4][4], BK=32, 32 kt,
// ZERO barriers in the K-loop.
//   A: sliding-window panel (144 rows, 18 KB) persistent in LDS, staged once
//      via gload_lds (pre-swizzled source, rule 21); swizzled ds_read_b128
//      (slot8 ^= row&7).
//   B: packed Wp (1 MB, L2-resident) coalesced dwordx4 fragment loads,
//      FOUR named register buffers p0..p3, prefetch distance 2 kt:
//      issue B(kt+2),B(kt+3) -> compute kt,kt+1 -> issue B(kt+4),B(kt+5)
//      -> compute kt+2,kt+3. Consumed set is always the OLDEST in flight,
//      so counted vmcnt leaves younger prefetches in flight.
// ~160 regs -> 3 blocks/CU (12 waves): traded TLP for 2x stall coverage.
__global__ __launch_bounds__(256, 3) void pe_gemm(
    const u16* __restrict__ xb, const u16* __restrict__ Wp,
    const float* __restrict__ beff, const float* __restrict__ pos,
    float* __restrict__ out) {
  __shared__ u16 ldsA[AROWS * 64];     // 18,432 B, persistent

  const int t    = threadIdx.x;
  const int w    = t >> 6;
  const int lane = t & 63;
  const int b    = blockIdx.z;
  const int l0   = blockIdx.y * 128;
  const int n0   = blockIdx.x * 128;
  const int wr   = w >> 1;             // 0..1 -> 64-row band
  const int wc   = w & 1;              // 0..1 -> 64-col band
  const int lr   = lane & 15;
  const int g    = lane >> 4;          // 0..3

  // A staging: chunk = 8 rows x 64 u16 (dest row lane>>3, slot lane&7)
  const int sra = lane >> 3;
  const int sca = ((lane & 7) ^ sra) * 8;

  const u16* Ab = xb + (size_t)b * (SEQ * DIM) + (size_t)l0 * 64;
  // this wave's packed-B base: hgrps [(n0>>4)+wc*4, +4)
  const u16* Bp = Wp + ((size_t)((n0 >> 4) + wc * 4) * 32) * 512 + lane * 8;

  // ---- prologue: stage all of A (18 chunks) + preload B kt=0,1 ----
  #pragma unroll
  for (int i = 0; i < 4; ++i) {
    int c = w * 4 + i;
    gload_lds16(Ab + (c * 8 + sra) * 64 + sca, &ldsA[c * 512]);
  }
  if (w < 2) {
    int c = 16 + w;
    gload_lds16(Ab + (c * 8 + sra) * 64 + sca, &ldsA[c * 512]);
  }

  bf16x8 p0[4], p1[4], p2[4], p3[4];
  #pragma unroll
  for (int n = 0; n < 4; ++n)
    p0[n] = *(const bf16x8*)(Bp + (size_t)(n * 32 + 0) * 512);
  #pragma unroll
  for (int n = 0; n < 4; ++n)
    p1[n] = *(const bf16x8*)(Bp + (size_t)(n * 32 + 1) * 512);

  __syncthreads();                     // A staged

  f32x4 acc[4][4] = {};
  const int rbase = wr * 64 + lr;

  #define A_READS(kt_, aF_)                                                   \
    _Pragma("unroll")                                                         \
    for (int m = 0; m < 4; ++m) {                                             \
      int r = rbase + m * 16 + ((kt_) >> 1);                                  \
      int s = ((((kt_) & 1) << 2) + g) ^ (r & 7);                             \
      aF_[m] = *(const bf16x8*)&ldsA[r * 64 + s * 8];                         \
    }
  #define B_LOADS(kt_, dst_)                                                  \
    _Pragma("unroll")                                                         \
    for (int n = 0; n < 4; ++n)                                               \
      dst_[n] = *(const bf16x8*)(Bp + (size_t)(n * 32 + (kt_)) * 512);
  #define MFMAS(aF_, bF_)                                                     \
    __builtin_amdgcn_s_setprio(1);                                            \
    _Pragma("unroll")                                                         \
    for (int m = 0; m < 4; ++m)                                               \
      _Pragma("unroll")                                                       \
      for (int n = 0; n < 4; ++n)                                             \
        acc[m][n] = __builtin_amdgcn_mfma_f32_16x16x32_bf16(aF_[m], bF_[n],   \
                                                            acc[m][n], 0, 0, 0); \
    __builtin_amdgcn_s_setprio(0);

  for (int kt = 0; kt < 32; kt += 4) {
    bf16x8 aF[4];
    // prefetch kt+2, kt+3 (always valid: kt <= 28 -> kt+3 <= 31)
    B_LOADS(kt + 2, p2);
    B_LOADS(kt + 3, p3);
    A_READS(kt, aF);     MFMAS(aF, p0);
    A_READS(kt + 1, aF); MFMAS(aF, p1);
    // prefetch kt+4, kt+5
    if (kt + 4 < 32) { B_LOADS(kt + 4, p0); }
    if (kt + 5 < 32) { B_LOADS(kt + 5, p1); }
    A_READS(kt + 2, aF); MFMAS(aF, p2);
    A_READS(kt + 3, aF); MFMAS(aF, p3);
  }
  #undef A_READS
  #undef B_LOADS
  #undef MFMAS

  // ---- epilogue: D row=(lane>>4)*4+r, col=lane&15 (m89) ----
  #pragma unroll
  for (int n = 0; n < 4; ++n) {
    const int h  = n0 + wc * 64 + n * 16 + lr;
    const float bv = beff[h];
    #pragma unroll
    for (int m = 0; m < 4; ++m) {
      const int rowb = l0 + wr * 64 + m * 16 + (g << 2);
      #pragma unroll
      for (int r = 0; r < 4; ++r) {
        const int l = rowb + r;
        if (l < MINLEN) {
          out[((size_t)b * MINLEN + l) * HOUT + h] =
              acc[m][n][r] + bv + pos[(size_t)l * HOUT + h];
        }
      }
    }
  }
}

extern "C" void kernel_launch(void* const* d_in, const int* in_sizes, int n_in,
                              void* d_out, int out_size, void* d_ws, size_t ws_size,
                              hipStream_t stream) {
  const float* x   = (const float*)d_in[0];
  const float* W0  = (const float*)d_in[1];
  const float* b0  = (const float*)d_in[2];
  const float* W1  = (const float*)d_in[3];
  const float* b1  = (const float*)d_in[4];
  const float* W2  = (const float*)d_in[5];
  const float* b2  = (const float*)d_in[6];
  const float* pos = (const float*)d_in[7];
  float* out = (float*)d_out;

  char*  ws  = (char*)d_ws;
  u16*   xbf = (u16*)(ws + XB_OFF);
  u16*   Wp  = (u16*)(ws + WF_OFF);
  float* be  = (float*)(ws + BE_OFF);

  // prep: 1002 xb blocks + 256 fold/pack blocks + 2 bias blocks
  hipLaunchKernelGGL(pe_prep, dim3(1260), dim3(256), 0, stream,
                     x, W0, W1, W2, b0, b1, b2, xbf, Wp, be);
  // 4 n-tiles x 8 m-tiles x 32 batch = 1024 blocks
  hipLaunchKernelGGL(pe_gemm, dim3(HOUT / 128, 8, BATCH), dim3(256), 0, stream,
                     xbf, Wp, be, pos, out);
}

// Round 12
// 57.180 us; speedup vs baseline: 1.7655x; 1.1099x over previous
//
#include <hip/hip_runtime.h>
#include <stdint.h>

typedef unsigned short u16;
typedef __attribute__((ext_vector_type(8))) short bf16x8;
typedef __attribute__((ext_vector_type(8))) u16  u16x8;
typedef __attribute__((ext_vector_type(4))) float f32x4;

// Problem constants
static constexpr int BATCH  = 32;
static constexpr int SEQ    = 1000;
static constexpr int DIM    = 64;
static constexpr int HOUT   = 512;
static constexpr int MINLEN = 985;   // 1000 - 16 + 1
static constexpr int AROWS  = 144;   // 128-row tile + 15 window ext + pad

// ws layout (bytes)
static constexpr size_t XB_OFF   = 0;                  // x bf16: 2,048,000 + 4096 pad u16
static constexpr size_t WF_OFF   = 4u << 20;           // Wp packed bf16: 512*1024 u16 = 1 MiB
static constexpr size_t BE_OFF   = 5u << 20;           // beff f32: 512
static constexpr int    XB_TOTAL = 2048000 + 4096;     // = 2048*1002, exact

__device__ inline u16 f2bf(float f) {
  union { float f; uint32_t u; } v; v.f = f;
  uint32_t r = v.u + 0x7fffu + ((v.u >> 16) & 1u);
  return (u16)(r >> 16);
}

// ---- prep (single kernel, 3 segments) -------------------------------------
// bid < 1002          : x f32 -> bf16 (+ zero pad tail)
// 1002 <= bid < 1258  : fold W, PACK into MFMA-fragment order:
//   packed u16 idx = ((h>>4)*32 + (k>>5))*512 + ((k>>3)&3)*128 + (h&15)*8 + (k&7)
//   -> fragment (hgrp, kt) is contiguous 1 KB; lane l reads 16B at l*8
// bid >= 1258         : beff = mean bias
__global__ void pe_prep(const float* __restrict__ x,
                        const float* __restrict__ W0, const float* __restrict__ W1,
                        const float* __restrict__ W2, const float* __restrict__ b0,
                        const float* __restrict__ b1, const float* __restrict__ b2,
                        u16* __restrict__ xb, u16* __restrict__ Wp,
                        float* __restrict__ beff) {
  int bid = blockIdx.x;
  if (bid < 1002) {
    int i = (bid * 256 + threadIdx.x) * 8;
    u16x8 o;
    if (i < 2048000) {
      const float4* p = (const float4*)(x + i);
      float4 a = p[0], c = p[1];
      o[0] = f2bf(a.x); o[1] = f2bf(a.y); o[2] = f2bf(a.z); o[3] = f2bf(a.w);
      o[4] = f2bf(c.x); o[5] = f2bf(c.y); o[6] = f2bf(c.z); o[7] = f2bf(c.w);
    } else {
      o = (u16x8)(0);
    }
    *(u16x8*)(xb + i) = o;
  } else if (bid < 1258) {
    int j  = (bid - 1002) * 256 + threadIdx.x;   // one 8-elem k-chunk
    int h  = j >> 7;
    int kc = j & 127;                            // k = kc*8 + e
    float v[8];
    const float4* w2 = (const float4*)(W2 + h * 1024 + kc * 8);
    float4 a = w2[0], c = w2[1];
    v[0]=a.x; v[1]=a.y; v[2]=a.z; v[3]=a.w; v[4]=c.x; v[5]=c.y; v[6]=c.z; v[7]=c.w;
    if (kc < 64) {
      const float4* w1 = (const float4*)(W1 + h * 512 + kc * 8);
      float4 d = w1[0], e = w1[1];
      v[0]+=d.x; v[1]+=d.y; v[2]+=d.z; v[3]+=d.w; v[4]+=e.x; v[5]+=e.y; v[6]+=e.z; v[7]+=e.w;
    }
    if (kc < 32) {
      const float4* w0 = (const float4*)(W0 + h * 256 + kc * 8);
      float4 d = w0[0], e = w0[1];
      v[0]+=d.x; v[1]+=d.y; v[2]+=d.z; v[3]+=d.w; v[4]+=e.x; v[5]+=e.y; v[6]+=e.z; v[7]+=e.w;
    }
    u16x8 o;
    #pragma unroll
    for (int e = 0; e < 8; ++e) o[e] = f2bf(v[e] * (1.0f / 3.0f));
    size_t dst = ((size_t)(h >> 4) * 32 + (kc >> 2)) * 512 + (kc & 3) * 128 + (h & 15) * 8;
    *(u16x8*)(Wp + dst) = o;
  } else {
    int h = (bid - 1258) * 256 + threadIdx.x;
    if (h < HOUT) beff[h] = (b0[h] + b1[h] + b2[h]) * (1.0f / 3.0f);
  }
}

__device__ inline void gload_lds16(const void* g, void* l) {
  __builtin_amdgcn_global_load_lds(
      (const __attribute__((address_space(1))) uint32_t*)g,
      (__attribute__((address_space(3))) uint32_t*)l, 16, 0, 0);
}

// ---- GEMM: out[b,l,h] = dot(window) + beff[h] + pos[l,h]
// Best-known configuration (R6, 54.8us): 128x128 tile, 4 waves (2m x 2n),
// wave 64x64 -> acc[4][4], BK=32, 32 kt, ZERO barriers in the K-loop.
//   A: sliding-window panel (144 rows, 18 KB) persistent in LDS, staged once
//      via gload_lds (pre-swizzled source, rule 21); swizzled ds_read_b128
//      (slot8 ^= row&7 -> conflict-free).
//   B: NOT staged; packed Wp (1 MB, L2-resident) coalesced dwordx4 fragment
//      loads, 1-kt register double buffer (bA/bB, static indexing).
// 64 VGPR + 18.4 KB LDS -> 4 blocks/CU = 16 waves/CU: TLP is the proven
// lever (R2-R11: every depth-for-residency trade measured negative).
__global__ __launch_bounds__(256, 4) void pe_gemm(
    const u16* __restrict__ xb, const u16* __restrict__ Wp,
    const float* __restrict__ beff, const float* __restrict__ pos,
    float* __restrict__ out) {
  __shared__ u16 ldsA[AROWS * 64];     // 18,432 B, persistent

  const int t    = threadIdx.x;
  const int w    = t >> 6;
  const int lane = t & 63;
  const int b    = blockIdx.z;
  const int l0   = blockIdx.y * 128;
  const int n0   = blockIdx.x * 128;
  const int wr   = w >> 1;             // 0..1 -> 64-row band
  const int wc   = w & 1;              // 0..1 -> 64-col band
  const int lr   = lane & 15;
  const int g    = lane >> 4;          // 0..3

  // A staging: chunk = 8 rows x 64 u16 (dest row lane>>3, slot lane&7)
  const int sra = lane >> 3;
  const int sca = ((lane & 7) ^ sra) * 8;

  const u16* Ab = xb + (size_t)b * (SEQ * DIM) + (size_t)l0 * 64;
  // this wave's packed-B base: hgrps [(n0>>4)+wc*4, +4)
  const u16* Bp = Wp + ((size_t)((n0 >> 4) + wc * 4) * 32) * 512 + lane * 8;

  // ---- prologue: stage all of A (18 chunks); preload B kt=0 frags ----
  #pragma unroll
  for (int i = 0; i < 4; ++i) {
    int c = w * 4 + i;
    gload_lds16(Ab + (c * 8 + sra) * 64 + sca, &ldsA[c * 512]);
  }
  if (w < 2) {
    int c = 16 + w;
    gload_lds16(Ab + (c * 8 + sra) * 64 + sca, &ldsA[c * 512]);
  }

  bf16x8 bA[4], bB[4];
  #pragma unroll
  for (int n = 0; n < 4; ++n)
    bA[n] = *(const bf16x8*)(Bp + (size_t)(n * 32) * 512);

  __syncthreads();                     // A staged (all waves' rows visible)

  f32x4 acc[4][4] = {};
  const int rbase = wr * 64 + lr;

  #define A_READS(kt_, aF_)                                                   \
    _Pragma("unroll")                                                         \
    for (int m = 0; m < 4; ++m) {                                             \
      int r = rbase + m * 16 + ((kt_) >> 1);                                  \
      int s = ((((kt_) & 1) << 2) + g) ^ (r & 7);                             \
      aF_[m] = *(const bf16x8*)&ldsA[r * 64 + s * 8];                         \
    }
  #define B_LOADS(kt_, dst_)                                                  \
    _Pragma("unroll")                                                         \
    for (int n = 0; n < 4; ++n)                                               \
      dst_[n] = *(const bf16x8*)(Bp + (size_t)(n * 32 + (kt_)) * 512);
  #define MFMAS(aF_, bF_)                                                     \
    __builtin_amdgcn_s_setprio(1);                                            \
    _Pragma("unroll")                                                         \
    for (int m = 0; m < 4; ++m)                                               \
      _Pragma("unroll")                                                       \
      for (int n = 0; n < 4; ++n)                                             \
        acc[m][n] = __builtin_amdgcn_mfma_f32_16x16x32_bf16(aF_[m], bF_[n],   \
                                                            acc[m][n], 0, 0, 0); \
    __builtin_amdgcn_s_setprio(0);

  for (int kt = 0; kt < 32; kt += 2) {
    bf16x8 aF[4];
    if (kt + 1 < 32) { B_LOADS(kt + 1, bB); }
    A_READS(kt, aF);
    MFMAS(aF, bA);
    if (kt + 2 < 32) { B_LOADS(kt + 2, bA); }
    A_READS(kt + 1, aF);
    MFMAS(aF, bB);
  }
  #undef A_READS
  #undef B_LOADS
  #undef MFMAS

  // ---- epilogue: D row=(lane>>4)*4+r, col=lane&15 (m89) ----
  #pragma unroll
  for (int n = 0; n < 4; ++n) {
    const int h  = n0 + wc * 64 + n * 16 + lr;
    const float bv = beff[h];
    #pragma unroll
    for (int m = 0; m < 4; ++m) {
      const int rowb = l0 + wr * 64 + m * 16 + (g << 2);
      #pragma unroll
      for (int r = 0; r < 4; ++r) {
        const int l = rowb + r;
        if (l < MINLEN) {
          out[((size_t)b * MINLEN + l) * HOUT + h] =
              acc[m][n][r] + bv + pos[(size_t)l * HOUT + h];
        }
      }
    }
  }
}

extern "C" void kernel_launch(void* const* d_in, const int* in_sizes, int n_in,
                              void* d_out, int out_size, void* d_ws, size_t ws_size,
                              hipStream_t stream) {
  const float* x   = (const float*)d_in[0];
  const float* W0  = (const float*)d_in[1];
  const float* b0  = (const float*)d_in[2];
  const float* W1  = (const float*)d_in[3];
  const float* b1  = (const float*)d_in[4];
  const float* W2  = (const float*)d_in[5];
  const float* b2  = (const float*)d_in[6];
  const float* pos = (const float*)d_in[7];
  float* out = (float*)d_out;

  char*  ws  = (char*)d_ws;
  u16*   xbf = (u16*)(ws + XB_OFF);
  u16*   Wp  = (u16*)(ws + WF_OFF);
  float* be  = (float*)(ws + BE_OFF);

  // prep: 1002 xb blocks + 256 fold/pack blocks + 2 bias blocks
  hipLaunchKernelGGL(pe_prep, dim3(1260), dim3(256), 0, stream,
                     x, W0, W1, W2, b0, b1, b2, xbf, Wp, be);
  // 4 n-tiles x 8 m-tiles x 32 batch = 1024 blocks = exactly 4/CU
  hipLaunchKernelGGL(pe_gemm, dim3(HOUT / 128, 8, BATCH), dim3(256), 0, stream,
                     xbf, Wp, be, pos, out);
}

// Round 13
// 51.972 us; speedup vs baseline: 1.9424x; 1.1002x over previous
//
#include <hip/hip_runtime.h>
#include <stdint.h>

typedef unsigned short u16;
typedef __attribute__((ext_vector_type(8))) short bf16x8;
typedef __attribute__((ext_vector_type(8))) u16  u16x8;
typedef __attribute__((ext_vector_type(4))) float f32x4;

// Problem constants
static constexpr int BATCH  = 32;
static constexpr int SEQ    = 1000;
static constexpr int DIM    = 64;
static constexpr int HOUT   = 512;
static constexpr int MINLEN = 985;   // 1000 - 16 + 1
static constexpr int AROWS  = 144;   // 128-row tile + 15 window ext + pad

// ws layout (bytes)
static constexpr size_t XB_OFF   = 0;                  // x bf16: 2,048,000 + 4096 pad u16
static constexpr size_t WF_OFF   = 4u << 20;           // Wp packed bf16: 1 MiB
static constexpr size_t BE_OFF   = 5u << 20;           // beff f32: 512
static constexpr int    XB_TOTAL = 2048000 + 4096;     // = 2048*1002, exact

__device__ inline u16 f2bf(float f) {
  union { float f; uint32_t u; } v; v.f = f;
  uint32_t r = v.u + 0x7fffu + ((v.u >> 16) & 1u);
  return (u16)(r >> 16);
}

// ---- prep (single kernel, 3 segments) -------------------------------------
// bid < 1002          : x f32 -> bf16 (+ zero pad tail)
// 1002 <= bid < 1258  : fold W, PACK into MFMA-fragment order:
//   packed u16 idx = ((h>>4)*32 + (k>>5))*512 + ((k>>3)&3)*128 + (h&15)*8 + (k&7)
//   -> fragment (hgrp, kt) is contiguous 1 KB; lane l reads 16B at l*8
// bid >= 1258         : beff = mean bias
__global__ void pe_prep(const float* __restrict__ x,
                        const float* __restrict__ W0, const float* __restrict__ W1,
                        const float* __restrict__ W2, const float* __restrict__ b0,
                        const float* __restrict__ b1, const float* __restrict__ b2,
                        u16* __restrict__ xb, u16* __restrict__ Wp,
                        float* __restrict__ beff) {
  int bid = blockIdx.x;
  if (bid < 1002) {
    int i = (bid * 256 + threadIdx.x) * 8;
    u16x8 o;
    if (i < 2048000) {
      const float4* p = (const float4*)(x + i);
      float4 a = p[0], c = p[1];
      o[0] = f2bf(a.x); o[1] = f2bf(a.y); o[2] = f2bf(a.z); o[3] = f2bf(a.w);
      o[4] = f2bf(c.x); o[5] = f2bf(c.y); o[6] = f2bf(c.z); o[7] = f2bf(c.w);
    } else {
      o = (u16x8)(0);
    }
    *(u16x8*)(xb + i) = o;
  } else if (bid < 1258) {
    int j  = (bid - 1002) * 256 + threadIdx.x;   // one 8-elem k-chunk
    int h  = j >> 7;
    int kc = j & 127;                            // k = kc*8 + e
    float v[8];
    const float4* w2 = (const float4*)(W2 + h * 1024 + kc * 8);
    float4 a = w2[0], c = w2[1];
    v[0]=a.x; v[1]=a.y; v[2]=a.z; v[3]=a.w; v[4]=c.x; v[5]=c.y; v[6]=c.z; v[7]=c.w;
    if (kc < 64) {
      const float4* w1 = (const float4*)(W1 + h * 512 + kc * 8);
      float4 d = w1[0], e = w1[1];
      v[0]+=d.x; v[1]+=d.y; v[2]+=d.z; v[3]+=d.w; v[4]+=e.x; v[5]+=e.y; v[6]+=e.z; v[7]+=e.w;
    }
    if (kc < 32) {
      const float4* w0 = (const float4*)(W0 + h * 256 + kc * 8);
      float4 d = w0[0], e = w0[1];
      v[0]+=d.x; v[1]+=d.y; v[2]+=d.z; v[3]+=d.w; v[4]+=e.x; v[5]+=e.y; v[6]+=e.z; v[7]+=e.w;
    }
    u16x8 o;
    #pragma unroll
    for (int e = 0; e < 8; ++e) o[e] = f2bf(v[e] * (1.0f / 3.0f));
    size_t dst = ((size_t)(h >> 4) * 32 + (kc >> 2)) * 512 + (kc & 3) * 128 + (h & 15) * 8;
    *(u16x8*)(Wp + dst) = o;
  } else {
    int h = (bid - 1258) * 256 + threadIdx.x;
    if (h < HOUT) beff[h] = (b0[h] + b1[h] + b2[h]) * (1.0f / 3.0f);
  }
}

__device__ inline void gload_lds16(const void* g, void* l) {
  __builtin_amdgcn_global_load_lds(
      (const __attribute__((address_space(1))) uint32_t*)g,
      (__attribute__((address_space(3))) uint32_t*)l, 16, 0, 0);
}

// ---- GEMM: out[b,l,h] = dot(window) + beff[h] + pos[l,h]
// R6 K-loop (best known) + SWAPPED-OPERAND EPILOGUE + l0-keyed XCD swizzle.
// 128x128 tile, 4 waves (2m x 2n), wave 64(l) x 64(h), BK=32, 32 kt,
// ZERO barriers in the K-loop.
//   A-operand = WEIGHT frags (packed Wp, L2-resident, coalesced dwordx4,
//               1-kt register double buffer bA/bB).
//   B-operand = WINDOW frags from the LDS sliding-window panel (144 rows,
//               staged once via gload_lds, pre-swizzled source rule 21,
//               swizzled ds_read_b128 slot8 ^= row&7).
//   => D[h][l]: lane's 4 acc regs = 4 CONSECUTIVE h -> float4 stores,
//      float4 pos/beff loads, l-bound check hoisted (4 instead of 64).
// XCD swizzle: bid&7 = l0 slice -> each XCD's 128 resident blocks share one
//   l0: per-XCD hot set = pos slice 256KB + xb slice 576KB + Wp 1MB (L2-fit).
// 64 VGPR + 18.4 KB LDS -> 4 blocks/CU = 16 waves/CU (the proven optimum).
__global__ __launch_bounds__(256, 4) void pe_gemm(
    const u16* __restrict__ xb, const u16* __restrict__ Wp,
    const float* __restrict__ beff, const float* __restrict__ pos,
    float* __restrict__ out) {
  __shared__ u16 ldsA[AROWS * 64];     // 18,432 B, persistent

  const int t    = threadIdx.x;
  const int w    = t >> 6;
  const int lane = t & 63;

  // l0-keyed decode: XCD (round-robin by bid%8) owns one l0 slice
  const int bid = blockIdx.x;
  const int l0  = (bid & 7) * 128;          // 8 m-tiles
  const int n0  = ((bid >> 3) & 3) * 128;   // 4 n-tiles
  const int b   = bid >> 5;                 // 32 batches

  const int wr   = w >> 1;             // 0..1 -> 64-row(l) band
  const int wc   = w & 1;              // 0..1 -> 64-col(h) band
  const int lr   = lane & 15;
  const int g    = lane >> 4;          // 0..3

  // A staging: chunk = 8 rows x 64 u16 (dest row lane>>3, slot lane&7)
  const int sra = lane >> 3;
  const int sca = ((lane & 7) ^ sra) * 8;

  const u16* Ab = xb + (size_t)b * (SEQ * DIM) + (size_t)l0 * 64;
  // this wave's packed-B base: hgrps [(n0>>4)+wc*4, +4)
  const u16* Bp = Wp + ((size_t)((n0 >> 4) + wc * 4) * 32) * 512 + lane * 8;

  // ---- prologue: stage all of A (18 chunks); preload W kt=0 frags ----
  #pragma unroll
  for (int i = 0; i < 4; ++i) {
    int c = w * 4 + i;
    gload_lds16(Ab + (c * 8 + sra) * 64 + sca, &ldsA[c * 512]);
  }
  if (w < 2) {
    int c = 16 + w;
    gload_lds16(Ab + (c * 8 + sra) * 64 + sca, &ldsA[c * 512]);
  }

  bf16x8 bA[4], bB[4];
  #pragma unroll
  for (int n = 0; n < 4; ++n)
    bA[n] = *(const bf16x8*)(Bp + (size_t)(n * 32) * 512);

  __syncthreads();                     // A staged (all waves' rows visible)

  f32x4 acc[4][4] = {};                // acc[mh (h frag)][nl (l frag)]
  const int rbase = wr * 64 + lr;

  #define A_READS(kt_, aF_)                                                   \
    _Pragma("unroll")                                                         \
    for (int n = 0; n < 4; ++n) {                                             \
      int r = rbase + n * 16 + ((kt_) >> 1);                                  \
      int s = ((((kt_) & 1) << 2) + g) ^ (r & 7);                             \
      aF_[n] = *(const bf16x8*)&ldsA[r * 64 + s * 8];                         \
    }
  #define B_LOADS(kt_, dst_)                                                  \
    _Pragma("unroll")                                                         \
    for (int n = 0; n < 4; ++n)                                               \
      dst_[n] = *(const bf16x8*)(Bp + (size_t)(n * 32 + (kt_)) * 512);
  // SWAPPED: weights as A-operand, window as B-operand -> D[h][l]
  #define MFMAS(aF_, wF_)                                                     \
    __builtin_amdgcn_s_setprio(1);                                            \
    _Pragma("unroll")                                                         \
    for (int m = 0; m < 4; ++m)                                               \
      _Pragma("unroll")                                                       \
      for (int n = 0; n < 4; ++n)                                             \
        acc[m][n] = __builtin_amdgcn_mfma_f32_16x16x32_bf16(wF_[m], aF_[n],   \
                                                            acc[m][n], 0, 0, 0); \
    __builtin_amdgcn_s_setprio(0);

  for (int kt = 0; kt < 32; kt += 2) {
    bf16x8 aF[4];
    if (kt + 1 < 32) { B_LOADS(kt + 1, bB); }
    A_READS(kt, aF);
    MFMAS(aF, bA);
    if (kt + 2 < 32) { B_LOADS(kt + 2, bA); }
    A_READS(kt + 1, aF);
    MFMAS(aF, bB);
  }
  #undef A_READS
  #undef B_LOADS
  #undef MFMAS

  // ---- epilogue: D row(h)=(lane>>4)*4+reg, col(l)=lane&15 (m89, swapped) --
  // lane's 4 acc regs = h4..h4+3 -> float4 store; l check hoisted.
  f32x4 bv[4];
  #pragma unroll
  for (int m = 0; m < 4; ++m)
    bv[m] = *(const f32x4*)&beff[n0 + wc * 64 + m * 16 + (g << 2)];

  #pragma unroll
  for (int n = 0; n < 4; ++n) {
    const int l = l0 + wr * 64 + n * 16 + lr;
    if (l < MINLEN) {
      const float* pr = pos + (size_t)l * HOUT;
      float*       orow = out + ((size_t)b * MINLEN + l) * HOUT;
      #pragma unroll
      for (int m = 0; m < 4; ++m) {
        const int h4 = n0 + wc * 64 + m * 16 + (g << 2);
        f32x4 pv = *(const f32x4*)&pr[h4];
        f32x4 o;
        o[0] = acc[m][n][0] + bv[m][0] + pv[0];
        o[1] = acc[m][n][1] + bv[m][1] + pv[1];
        o[2] = acc[m][n][2] + bv[m][2] + pv[2];
        o[3] = acc[m][n][3] + bv[m][3] + pv[3];
        *(f32x4*)&orow[h4] = o;
      }
    }
  }
}

extern "C" void kernel_launch(void* const* d_in, const int* in_sizes, int n_in,
                              void* d_out, int out_size, void* d_ws, size_t ws_size,
                              hipStream_t stream) {
  const float* x   = (const float*)d_in[0];
  const float* W0  = (const float*)d_in[1];
  const float* b0  = (const float*)d_in[2];
  const float* W1  = (const float*)d_in[3];
  const float* b1  = (const float*)d_in[4];
  const float* W2  = (const float*)d_in[5];
  const float* b2  = (const float*)d_in[6];
  const float* pos = (const float*)d_in[7];
  float* out = (float*)d_out;

  char*  ws  = (char*)d_ws;
  u16*   xbf = (u16*)(ws + XB_OFF);
  u16*   Wp  = (u16*)(ws + WF_OFF);
  float* be  = (float*)(ws + BE_OFF);

  // prep: 1002 xb blocks + 256 fold/pack blocks + 2 bias blocks
  hipLaunchKernelGGL(pe_prep, dim3(1260), dim3(256), 0, stream,
                     x, W0, W1, W2, b0, b1, b2, xbf, Wp, be);
  // 1024 blocks, 1D: bid&7 = l0 slice (XCD-keyed), then n, then b
  hipLaunchKernelGGL(pe_gemm, dim3(1024), dim3(256), 0, stream,
                     xbf, Wp, be, pos, out);
}

// Round 14
// 51.483 us; speedup vs baseline: 1.9609x; 1.0095x over previous
//
#include <hip/hip_runtime.h>
#include <stdint.h>

typedef unsigned short u16;
typedef __attribute__((ext_vector_type(8))) short bf16x8;
typedef __attribute__((ext_vector_type(8))) u16  u16x8;
typedef __attribute__((ext_vector_type(4))) float f32x4;

// Problem constants
static constexpr int BATCH  = 32;
static constexpr int SEQ    = 1000;
static constexpr int DIM    = 64;
static constexpr int HOUT   = 512;
static constexpr int MINLEN = 985;   // 1000 - 16 + 1
static constexpr int AROWS  = 144;   // 128-row tile + 15 window ext + pad

// ws layout (bytes)
static constexpr size_t XB_OFF   = 0;                  // x bf16: 2,048,000 + 4096 pad u16
static constexpr size_t WF_OFF   = 4u << 20;           // Wp packed bf16: 1 MiB
static constexpr size_t BE_OFF   = 5u << 20;           // beff f32: 512
static constexpr int    XB_TOTAL = 2048000 + 4096;     // = 2048*1002, exact

__device__ inline u16 f2bf(float f) {
  union { float f; uint32_t u; } v; v.f = f;
  uint32_t r = v.u + 0x7fffu + ((v.u >> 16) & 1u);
  return (u16)(r >> 16);
}

// ---- prep (single kernel, 3 segments) -------------------------------------
// bid < 1002          : x f32 -> bf16 (+ zero pad tail)
// 1002 <= bid < 1258  : fold W, PACK into MFMA-fragment order:
//   packed u16 idx = ((h>>4)*32 + (k>>5))*512 + ((k>>3)&3)*128 + (h&15)*8 + (k&7)
//   -> fragment (hgrp, kt) is contiguous 1 KB; lane l reads 16B at l*8
// bid >= 1258         : beff = mean bias
__global__ void pe_prep(const float* __restrict__ x,
                        const float* __restrict__ W0, const float* __restrict__ W1,
                        const float* __restrict__ W2, const float* __restrict__ b0,
                        const float* __restrict__ b1, const float* __restrict__ b2,
                        u16* __restrict__ xb, u16* __restrict__ Wp,
                        float* __restrict__ beff) {
  int bid = blockIdx.x;
  if (bid < 1002) {
    int i = (bid * 256 + threadIdx.x) * 8;
    u16x8 o;
    if (i < 2048000) {
      const float4* p = (const float4*)(x + i);
      float4 a = p[0], c = p[1];
      o[0] = f2bf(a.x); o[1] = f2bf(a.y); o[2] = f2bf(a.z); o[3] = f2bf(a.w);
      o[4] = f2bf(c.x); o[5] = f2bf(c.y); o[6] = f2bf(c.z); o[7] = f2bf(c.w);
    } else {
      o = (u16x8)(0);
    }
    *(u16x8*)(xb + i) = o;
  } else if (bid < 1258) {
    int j  = (bid - 1002) * 256 + threadIdx.x;   // one 8-elem k-chunk
    int h  = j >> 7;
    int kc = j & 127;                            // k = kc*8 + e
    float v[8];
    const float4* w2 = (const float4*)(W2 + h * 1024 + kc * 8);
    float4 a = w2[0], c = w2[1];
    v[0]=a.x; v[1]=a.y; v[2]=a.z; v[3]=a.w; v[4]=c.x; v[5]=c.y; v[6]=c.z; v[7]=c.w;
    if (kc < 64) {
      const float4* w1 = (const float4*)(W1 + h * 512 + kc * 8);
      float4 d = w1[0], e = w1[1];
      v[0]+=d.x; v[1]+=d.y; v[2]+=d.z; v[3]+=d.w; v[4]+=e.x; v[5]+=e.y; v[6]+=e.z; v[7]+=e.w;
    }
    if (kc < 32) {
      const float4* w0 = (const float4*)(W0 + h * 256 + kc * 8);
      float4 d = w0[0], e = w0[1];
      v[0]+=d.x; v[1]+=d.y; v[2]+=d.z; v[3]+=d.w; v[4]+=e.x; v[5]+=e.y; v[6]+=e.z; v[7]+=e.w;
    }
    u16x8 o;
    #pragma unroll
    for (int e = 0; e < 8; ++e) o[e] = f2bf(v[e] * (1.0f / 3.0f));
    size_t dst = ((size_t)(h >> 4) * 32 + (kc >> 2)) * 512 + (kc & 3) * 128 + (h & 15) * 8;
    *(u16x8*)(Wp + dst) = o;
  } else {
    int h = (bid - 1258) * 256 + threadIdx.x;
    if (h < HOUT) beff[h] = (b0[h] + b1[h] + b2[h]) * (1.0f / 3.0f);
  }
}

__device__ inline void gload_lds16(const void* g, void* l) {
  __builtin_amdgcn_global_load_lds(
      (const __attribute__((address_space(1))) uint32_t*)g,
      (__attribute__((address_space(3))) uint32_t*)l, 16, 0, 0);
}

// ---- GEMM: out[b,l,h] = dot(window) + beff[h] + pos[l,h]
// R13 structure (best, 52.0us) + fully-unrolled K-loop + nontemporal stores.
// 128x128 tile, 4 waves (2m x 2n), wave 64(l) x 64(h), BK=32, 32 kt,
// ZERO barriers in the K-loop.
//   A-operand = WEIGHT frags (packed Wp, L2-resident, coalesced dwordx4,
//               1-kt register double buffer bA/bB).
//   B-operand = WINDOW frags from the LDS sliding-window panel (144 rows,
//               staged once via gload_lds, pre-swizzled source rule 21,
//               swizzled ds_read_b128 slot8 ^= row&7).
//   => D[h][l]: lane's 4 acc regs = 4 CONSECUTIVE h -> float4 nt-stores,
//      float4 pos/beff loads, l-bound check hoisted.
// XCD swizzle: bid&7 = l0 slice; per-XCD hot set ~1.8 MB (L2-fit).
// 64 VGPR + 64 AGPR = 128 unified regs exactly -> 4 blocks/CU = 16 waves/CU
// (the measured residency optimum; every reg-for-depth trade lost, R7/R11).
__global__ __launch_bounds__(256, 4) void pe_gemm(
    const u16* __restrict__ xb, const u16* __restrict__ Wp,
    const float* __restrict__ beff, const float* __restrict__ pos,
    float* __restrict__ out) {
  __shared__ u16 ldsA[AROWS * 64];     // 18,432 B, persistent

  const int t    = threadIdx.x;
  const int w    = t >> 6;
  const int lane = t & 63;

  // l0-keyed decode: XCD (round-robin by bid%8) owns one l0 slice
  const int bid = blockIdx.x;
  const int l0  = (bid & 7) * 128;          // 8 m-tiles
  const int n0  = ((bid >> 3) & 3) * 128;   // 4 n-tiles
  const int b   = bid >> 5;                 // 32 batches

  const int wr   = w >> 1;             // 0..1 -> 64-row(l) band
  const int wc   = w & 1;              // 0..1 -> 64-col(h) band
  const int lr   = lane & 15;
  const int g    = lane >> 4;          // 0..3

  // A staging: chunk = 8 rows x 64 u16 (dest row lane>>3, slot lane&7)
  const int sra = lane >> 3;
  const int sca = ((lane & 7) ^ sra) * 8;

  const u16* Ab = xb + (size_t)b * (SEQ * DIM) + (size_t)l0 * 64;
  // this wave's packed-B base: hgrps [(n0>>4)+wc*4, +4)
  const u16* Bp = Wp + ((size_t)((n0 >> 4) + wc * 4) * 32) * 512 + lane * 8;

  // ---- prologue: stage all of A (18 chunks); preload W kt=0 frags ----
  #pragma unroll
  for (int i = 0; i < 4; ++i) {
    int c = w * 4 + i;
    gload_lds16(Ab + (c * 8 + sra) * 64 + sca, &ldsA[c * 512]);
  }
  if (w < 2) {
    int c = 16 + w;
    gload_lds16(Ab + (c * 8 + sra) * 64 + sca, &ldsA[c * 512]);
  }

  bf16x8 bA[4], bB[4];
  #pragma unroll
  for (int n = 0; n < 4; ++n)
    bA[n] = *(const bf16x8*)(Bp + (size_t)(n * 32) * 512);

  __syncthreads();                     // A staged (all waves' rows visible)

  f32x4 acc[4][4] = {};                // acc[mh (h frag)][nl (l frag)]
  const int rbase = wr * 64 + lr;

  #define A_READS(kt_, aF_)                                                   \
    _Pragma("unroll")                                                         \
    for (int n = 0; n < 4; ++n) {                                             \
      int r = rbase + n * 16 + ((kt_) >> 1);                                  \
      int s = ((((kt_) & 1) << 2) + g) ^ (r & 7);                             \
      aF_[n] = *(const bf16x8*)&ldsA[r * 64 + s * 8];                         \
    }
  #define B_LOADS(kt_, dst_)                                                  \
    _Pragma("unroll")                                                         \
    for (int n = 0; n < 4; ++n)                                               \
      dst_[n] = *(const bf16x8*)(Bp + (size_t)(n * 32 + (kt_)) * 512);
  // SWAPPED: weights as A-operand, window as B-operand -> D[h][l]
  #define MFMAS(aF_, wF_)                                                     \
    __builtin_amdgcn_s_setprio(1);                                            \
    _Pragma("unroll")                                                         \
    for (int m = 0; m < 4; ++m)                                               \
      _Pragma("unroll")                                                       \
      for (int n = 0; n < 4; ++n)                                             \
        acc[m][n] = __builtin_amdgcn_mfma_f32_16x16x32_bf16(wF_[m], aF_[n],   \
                                                            acc[m][n], 0, 0, 0); \
    __builtin_amdgcn_s_setprio(0);

  #pragma unroll
  for (int kt = 0; kt < 32; kt += 2) {
    bf16x8 aF[4];
    if (kt + 1 < 32) { B_LOADS(kt + 1, bB); }
    A_READS(kt, aF);
    MFMAS(aF, bA);
    if (kt + 2 < 32) { B_LOADS(kt + 2, bA); }
    A_READS(kt + 1, aF);
    MFMAS(aF, bB);
  }
  #undef A_READS
  #undef B_LOADS
  #undef MFMAS

  // ---- epilogue: D row(h)=(lane>>4)*4+reg, col(l)=lane&15 (m89, swapped) --
  // lane's 4 acc regs = h4..h4+3 -> float4 nt-store; l check hoisted.
  f32x4 bv[4];
  #pragma unroll
  for (int m = 0; m < 4; ++m)
    bv[m] = *(const f32x4*)&beff[n0 + wc * 64 + m * 16 + (g << 2)];

  #pragma unroll
  for (int n = 0; n < 4; ++n) {
    const int l = l0 + wr * 64 + n * 16 + lr;
    if (l < MINLEN) {
      const float* pr = pos + (size_t)l * HOUT;
      float*       orow = out + ((size_t)b * MINLEN + l) * HOUT;
      #pragma unroll
      for (int m = 0; m < 4; ++m) {
        const int h4 = n0 + wc * 64 + m * 16 + (g << 2);
        f32x4 pv = *(const f32x4*)&pr[h4];
        f32x4 o;
        o[0] = acc[m][n][0] + bv[m][0] + pv[0];
        o[1] = acc[m][n][1] + bv[m][1] + pv[1];
        o[2] = acc[m][n][2] + bv[m][2] + pv[2];
        o[3] = acc[m][n][3] + bv[m][3] + pv[3];
        __builtin_nontemporal_store(o, (f32x4*)&orow[h4]);
      }
    }
  }
}

extern "C" void kernel_launch(void* const* d_in, const int* in_sizes, int n_in,
                              void* d_out, int out_size, void* d_ws, size_t ws_size,
                              hipStream_t stream) {
  const float* x   = (const float*)d_in[0];
  const float* W0  = (const float*)d_in[1];
  const float* b0  = (const float*)d_in[2];
  const float* W1  = (const float*)d_in[3];
  const float* b1  = (const float*)d_in[4];
  const float* W2  = (const float*)d_in[5];
  const float* b2  = (const float*)d_in[6];
  const float* pos = (const float*)d_in[7];
  float* out = (float*)d_out;

  char*  ws  = (char*)d_ws;
  u16*   xbf = (u16*)(ws + XB_OFF);
  u16*   Wp  = (u16*)(ws + WF_OFF);
  float* be  = (float*)(ws + BE_OFF);

  // prep: 1002 xb blocks + 256 fold/pack blocks + 2 bias blocks
  hipLaunchKernelGGL(pe_prep, dim3(1260), dim3(256), 0, stream,
                     x, W0, W1, W2, b0, b1, b2, xbf, Wp, be);
  // 1024 blocks, 1D: bid&7 = l0 slice (XCD-keyed), then n, then b
  hipLaunchKernelGGL(pe_gemm, dim3(1024), dim3(256), 0, stream,
                     xbf, Wp, be, pos, out);
}